// Round 1
// baseline (771.476 us; speedup 1.0000x reference)
//
#include <hip/hip_runtime.h>

#define B_    256
#define NKV   128
#define NQ    512
#define CDIM  192
#define QCDIM 96
#define NH    6
#define DH    32
#define SCALE 0.17677669529663687f

// Fused per-(batch, head) kernel: kv-proj (head slice), q-proj (head slice),
// S = QK^T + bias, softmax, O = P V.  Epilogue:
//   USE_WS=1: write O_h to ws (B,512,192); final projection in second kernel.
//   USE_WS=0: multiply O_h by w_proj head-slice and atomicAdd into zeroed out.
template <int USE_WS>
__global__ __launch_bounds__(512)
void attn_fused(const float* __restrict__ kv, const float* __restrict__ q,
                const float* __restrict__ w_kv, const float* __restrict__ b_kv,
                const float* __restrict__ w_q, const float* __restrict__ b_q,
                const float* __restrict__ w_proj, const float* __restrict__ b_proj,
                const float* __restrict__ bias_table, const int* __restrict__ rel_index,
                float* __restrict__ ws_o, float* __restrict__ out)
{
    const int b  = blockIdx.x;
    const int h  = blockIdx.y;
    const int t  = threadIdx.x;
    const int rt = t >> 4;    // 0..31 (row tile)
    const int ct = t & 15;    // 0..15 (col tile)
    const int r0 = rt * 4;

    __shared__ float sKT[DH][132];      // K transposed: sKT[d][n], n in [0,128)
    __shared__ float sV[NKV][DH + 1];   // V row-major
    __shared__ float sQP[128][DH + 1];  // q-proj chunk; reused as O chunk (path B)
    __shared__ float sStage[128][20];   // global->LDS staging (16 wide + pad)
    __shared__ float sBig[128 * 132];   // union: weight staging / S matrix

    // ---------------- Phase 0: k_h, v_h = kv_b @ w_kv[:, head cols] ----------
    {
        // stage w_kv slice: layout sBig[c*64 + j]; j<32 -> k col, j>=32 -> v col
        for (int i = t; i < CDIM * 64; i += 512) {
            const int c = i >> 6, j = i & 63;
            const int col = (j < DH) ? (h * DH + j) : (CDIM + h * DH + (j - DH));
            sBig[i] = w_kv[c * (2 * CDIM) + col];
        }
        const int j0 = ct * 4;
        float acc[4][4];
        #pragma unroll
        for (int i = 0; i < 4; ++i)
            #pragma unroll
            for (int j = 0; j < 4; ++j) acc[i][j] = 0.f;

        for (int ck = 0; ck < CDIM / 16; ++ck) {
            __syncthreads();
            {
                const int i = t * 4;                 // 2048 = 128*16 exactly
                const int r = i >> 4, cc = i & 15;
                *(float4*)&sStage[r][cc] =
                    *(const float4*)&kv[(size_t)(b * NKV + r) * CDIM + ck * 16 + cc];
            }
            __syncthreads();
            #pragma unroll
            for (int cc = 0; cc < 16; ++cc) {
                const float4 w4 = *(const float4*)&sBig[(ck * 16 + cc) * 64 + j0];
                #pragma unroll
                for (int i = 0; i < 4; ++i) {
                    const float a = sStage[r0 + i][cc];
                    acc[i][0] += a * w4.x;
                    acc[i][1] += a * w4.y;
                    acc[i][2] += a * w4.z;
                    acc[i][3] += a * w4.w;
                }
            }
        }
        #pragma unroll
        for (int i = 0; i < 4; ++i)
            #pragma unroll
            for (int j = 0; j < 4; ++j) {
                const int jj = j0 + j;
                if (jj < DH)
                    sKT[jj][r0 + i] = acc[i][j] + b_kv[h * DH + jj];
                else
                    sV[r0 + i][jj - DH] = acc[i][j] + b_kv[CDIM + h * DH + (jj - DH)];
            }
    }

    // ---------------- Phase 1: q-chunks of 128 rows ----------------
    for (int qc = 0; qc < 4; ++qc) {
        __syncthreads();  // all prior users of sBig / sQP are done

        // (a) qp chunk = q[rows] @ w_q[:, head cols] * scale
        {
            for (int i = t; i < QCDIM * DH; i += 512) {   // 3072: sBig[c*32+j]
                const int c = i >> 5, j = i & 31;
                sBig[i] = w_q[c * CDIM + h * DH + j];
            }
            const int c0 = ct * 2;
            float qacc[4][2];
            #pragma unroll
            for (int i = 0; i < 4; ++i) { qacc[i][0] = 0.f; qacc[i][1] = 0.f; }

            for (int ck = 0; ck < QCDIM / 16; ++ck) {
                __syncthreads();
                {
                    const int i = t * 4;
                    const int r = i >> 4, cc = i & 15;
                    *(float4*)&sStage[r][cc] =
                        *(const float4*)&q[(size_t)(b * NQ + qc * 128 + r) * QCDIM + ck * 16 + cc];
                }
                __syncthreads();
                #pragma unroll
                for (int cc = 0; cc < 16; ++cc) {
                    const float w0 = sBig[(ck * 16 + cc) * DH + c0];
                    const float w1 = sBig[(ck * 16 + cc) * DH + c0 + 1];
                    #pragma unroll
                    for (int i = 0; i < 4; ++i) {
                        const float a = sStage[r0 + i][cc];
                        qacc[i][0] += a * w0;
                        qacc[i][1] += a * w1;
                    }
                }
            }
            #pragma unroll
            for (int i = 0; i < 4; ++i) {
                sQP[r0 + i][c0]     = (qacc[i][0] + b_q[h * DH + c0]) * SCALE;
                sQP[r0 + i][c0 + 1] = (qacc[i][1] + b_q[h * DH + c0 + 1]) * SCALE;
            }
        }
        __syncthreads();

        // (b) S = QP @ K^T + bias ; softmax rows ; P -> sBig
        {
            const int k0 = ct * 8;
            float s[4][8];
            #pragma unroll
            for (int i = 0; i < 4; ++i)
                #pragma unroll
                for (int j = 0; j < 8; ++j) s[i][j] = 0.f;

            #pragma unroll
            for (int dd = 0; dd < DH; ++dd) {
                const float4 kb0 = *(const float4*)&sKT[dd][k0];
                const float4 kb1 = *(const float4*)&sKT[dd][k0 + 4];
                #pragma unroll
                for (int i = 0; i < 4; ++i) {
                    const float a = sQP[r0 + i][dd];
                    s[i][0] += a * kb0.x; s[i][1] += a * kb0.y;
                    s[i][2] += a * kb0.z; s[i][3] += a * kb0.w;
                    s[i][4] += a * kb1.x; s[i][5] += a * kb1.y;
                    s[i][6] += a * kb1.z; s[i][7] += a * kb1.w;
                }
            }
            #pragma unroll
            for (int i = 0; i < 4; ++i) {
                const int qrow = qc * 128 + r0 + i;
                float m = -1e30f;
                #pragma unroll
                for (int j = 0; j < 8; ++j) {
                    const int idx = rel_index[qrow * NKV + k0 + j];
                    s[i][j] += bias_table[idx * NH + h];
                    m = fmaxf(m, s[i][j]);
                }
                #pragma unroll
                for (int off = 1; off < 16; off <<= 1)
                    m = fmaxf(m, __shfl_xor(m, off, 64));
                float sum = 0.f;
                #pragma unroll
                for (int j = 0; j < 8; ++j) {
                    s[i][j] = __expf(s[i][j] - m);
                    sum += s[i][j];
                }
                #pragma unroll
                for (int off = 1; off < 16; off <<= 1)
                    sum += __shfl_xor(sum, off, 64);
                const float inv = 1.f / sum;
                #pragma unroll
                for (int j = 0; j < 8; ++j) s[i][j] *= inv;
            }
            #pragma unroll
            for (int i = 0; i < 4; ++i) {
                *(float4*)&sBig[(r0 + i) * 132 + k0] =
                    make_float4(s[i][0], s[i][1], s[i][2], s[i][3]);
                *(float4*)&sBig[(r0 + i) * 132 + k0 + 4] =
                    make_float4(s[i][4], s[i][5], s[i][6], s[i][7]);
            }
        }
        __syncthreads();

        // (c) O = P @ V   (per thread: 4 rows x 2 cols)
        float oacc[4][2];
        #pragma unroll
        for (int i = 0; i < 4; ++i) { oacc[i][0] = 0.f; oacc[i][1] = 0.f; }
        {
            const int c0 = ct * 2;
            for (int kk = 0; kk < NKV; kk += 4) {
                #pragma unroll
                for (int l = 0; l < 4; ++l) {
                    const float v0 = sV[kk + l][c0];
                    const float v1 = sV[kk + l][c0 + 1];
                    #pragma unroll
                    for (int i = 0; i < 4; ++i) {
                        const float pv = sBig[(r0 + i) * 132 + kk + l];
                        oacc[i][0] += pv * v0;
                        oacc[i][1] += pv * v1;
                    }
                }
            }
        }

        // (d) epilogue
        if (USE_WS) {
            const int c0 = ct * 2;
            #pragma unroll
            for (int i = 0; i < 4; ++i) {
                const size_t row = (size_t)(b * NQ + qc * 128 + r0 + i);
                ws_o[row * CDIM + h * DH + c0]     = oacc[i][0];
                ws_o[row * CDIM + h * DH + c0 + 1] = oacc[i][1];
            }
        } else {
            const int c0 = ct * 2;
            #pragma unroll
            for (int i = 0; i < 4; ++i) {
                sQP[r0 + i][c0]     = oacc[i][0];   // sQP reused as O chunk
                sQP[r0 + i][c0 + 1] = oacc[i][1];
            }
            __syncthreads();
            for (int i = t; i < DH * QCDIM; i += 512)       // w_proj head rows are contiguous
                sBig[i] = w_proj[h * DH * QCDIM + i];       // sBig[dd*96 + c]
            __syncthreads();
            const int f0 = ct * 6;
            float facc[4][6];
            #pragma unroll
            for (int i = 0; i < 4; ++i)
                #pragma unroll
                for (int j = 0; j < 6; ++j) facc[i][j] = 0.f;
            #pragma unroll
            for (int dd = 0; dd < DH; ++dd) {
                float wv[6];
                #pragma unroll
                for (int j = 0; j < 6; ++j) wv[j] = sBig[dd * QCDIM + f0 + j];
                #pragma unroll
                for (int i = 0; i < 4; ++i) {
                    const float a = sQP[r0 + i][dd];
                    #pragma unroll
                    for (int j = 0; j < 6; ++j) facc[i][j] += a * wv[j];
                }
            }
            #pragma unroll
            for (int i = 0; i < 4; ++i)
                #pragma unroll
                for (int j = 0; j < 6; ++j)
                    atomicAdd(&out[(size_t)(b * NQ + qc * 128 + r0 + i) * QCDIM + f0 + j],
                              facc[i][j]);
        }
    }
}

// Path A second kernel: out = ws_o (B*512, 192) @ w_proj (192, 96) + b_proj
__global__ __launch_bounds__(256)
void final_proj(const float* __restrict__ ws_o, const float* __restrict__ w_proj,
                const float* __restrict__ b_proj, float* __restrict__ out)
{
    const int row0 = blockIdx.x * 64;
    const int t  = threadIdx.x;
    const int rt = t >> 4, ct = t & 15;
    const int r0 = rt * 4, c0 = ct * 6;
    __shared__ float sA[64][36];
    __shared__ float sB[32 * QCDIM];
    float acc[4][6];
    #pragma unroll
    for (int i = 0; i < 4; ++i)
        #pragma unroll
        for (int j = 0; j < 6; ++j) acc[i][j] = 0.f;

    for (int ck = 0; ck < CDIM / 32; ++ck) {
        __syncthreads();
        {
            const int i = t * 8;                  // 2048 = 64*32 exactly
            const int r = i >> 5, cc = i & 31;
            *(float4*)&sA[r][cc] =
                *(const float4*)&ws_o[(size_t)(row0 + r) * CDIM + ck * 32 + cc];
            *(float4*)&sA[r][cc + 4] =
                *(const float4*)&ws_o[(size_t)(row0 + r) * CDIM + ck * 32 + cc + 4];
        }
        for (int i = t; i < 32 * QCDIM; i += 256)
            sB[i] = w_proj[ck * 32 * QCDIM + i];
        __syncthreads();
        #pragma unroll
        for (int cc = 0; cc < 32; ++cc) {
            float wv[6];
            #pragma unroll
            for (int j = 0; j < 6; ++j) wv[j] = sB[cc * QCDIM + c0 + j];
            #pragma unroll
            for (int i = 0; i < 4; ++i) {
                const float a = sA[r0 + i][cc];
                #pragma unroll
                for (int j = 0; j < 6; ++j) acc[i][j] += a * wv[j];
            }
        }
    }
    #pragma unroll
    for (int i = 0; i < 4; ++i)
        #pragma unroll
        for (int j = 0; j < 6; ++j)
            out[(size_t)(row0 + r0 + i) * QCDIM + c0 + j] = acc[i][j] + b_proj[c0 + j];
}

__global__ void zero_f32(float* __restrict__ p, int n)
{
    const int i = blockIdx.x * blockDim.x + threadIdx.x;
    if (i < n) p[i] = 0.f;
}

extern "C" void kernel_launch(void* const* d_in, const int* in_sizes, int n_in,
                              void* d_out, int out_size, void* d_ws, size_t ws_size,
                              hipStream_t stream)
{
    const float* kv       = (const float*)d_in[0];
    const float* q        = (const float*)d_in[1];
    const float* w_kv     = (const float*)d_in[2];
    const float* b_kv     = (const float*)d_in[3];
    const float* w_q      = (const float*)d_in[4];
    const float* b_q      = (const float*)d_in[5];
    const float* w_proj   = (const float*)d_in[6];
    const float* b_proj   = (const float*)d_in[7];
    const float* bias_tab = (const float*)d_in[8];
    const int*   rel_idx  = (const int*)d_in[9];
    float* out = (float*)d_out;

    const size_t need = (size_t)B_ * NQ * CDIM * sizeof(float);  // 100.7 MB
    if (ws_size >= need) {
        float* ws_o = (float*)d_ws;
        attn_fused<1><<<dim3(B_, NH), 512, 0, stream>>>(
            kv, q, w_kv, b_kv, w_q, b_q, w_proj, b_proj, bias_tab, rel_idx, ws_o, out);
        final_proj<<<dim3((B_ * NQ) / 64), 256, 0, stream>>>(ws_o, w_proj, b_proj, out);
    } else {
        const int n = B_ * NQ * QCDIM;
        zero_f32<<<(n + 511) / 512, 512, 0, stream>>>(out, n);
        attn_fused<0><<<dim3(B_, NH), 512, 0, stream>>>(
            kv, q, w_kv, b_kv, w_q, b_q, w_proj, b_proj, bias_tab, rel_idx, nullptr, out);
    }
}

// Round 2
// 257.522 us; speedup vs baseline: 2.9958x; 2.9958x over previous
//
#include <hip/hip_runtime.h>
#include <hip/hip_bf16.h>

#define B_    256
#define NKV   128
#define NQ    512
#define CDIM  192
#define QCDIM 96
#define NH    6
#define DH    32
#define SCALE 0.17677669529663687f

typedef __hip_bfloat16 bf16;
typedef __attribute__((ext_vector_type(8))) short s16x8;
typedef __attribute__((ext_vector_type(4))) float f32x4;
#define MFMA16(a, b, c) __builtin_amdgcn_mfma_f32_16x16x32_bf16(a, b, c, 0, 0, 0)

// ---- workspace layout (bytes) ----
#define OFF_BIAS  0                         // fp32 [NH][512][128]  = 1,572,864
#define OFF_WKVT  1572864                   // bf16 [NH][64][192]   = 147,456
#define OFF_WQT   (OFF_WKVT + 147456)       // bf16 [NH][32][96]    = 36,864 (pre-scaled)
#define OFF_WPT   (OFF_WQT + 36864)         // bf16 [96][192]       = 36,864
#define OFF_O     2097152                   // bf16 [B_*NQ][192]    = 50,331,648

// ---- LDS layout for attn_fused (bytes); strides padded for <=2-way banks ----
#define LDS_K    0                          // bf16 [128][40]  K':  [kvrow][d]
#define LDS_VT   10240                      // bf16 [32][136]  V'^T:[d][kvrow]
#define LDS_STG  18944                      // bf16 [128][104] staging (union w/ sP)
#define LDS_P    18944                      // bf16 [128][136] P
#define LDS_WKV  53760                      // bf16 [64][200]  wkvT (union below)
#define LDS_WQ   53760                      // bf16 [32][104]  wqT
#define LDS_SQ   60416                      // bf16 [128][40]  Q' (scaled)
#define LDS_TOT  79360                      // 77.5 KB -> 2 blocks/CU

__global__ __launch_bounds__(256)
void precomp_bias(const float* __restrict__ bias_table, const int* __restrict__ rel_index,
                  float* __restrict__ biasM)
{
    const int i = blockIdx.x * 256 + threadIdx.x;      // grid covers NH*NQ*NKV = 393216
    const int h   = i >> 16;                           // NQ*NKV = 65536
    const int rem = i & 65535;
    biasM[i] = bias_table[rel_index[rem] * NH + h];
}

__global__ __launch_bounds__(256)
void precomp_w(const float* __restrict__ w_kv, const float* __restrict__ w_q,
               const float* __restrict__ w_proj,
               bf16* __restrict__ wkvT, bf16* __restrict__ wqT, bf16* __restrict__ wpT)
{
    const int i = blockIdx.x * 256 + threadIdx.x;      // grid covers 110592
    if (i < NH * 64 * CDIM) {                          // 73728: wkvT[h][j][k]
        const int k = i % CDIM, jh = i / CDIM;
        const int j = jh & 63, h = jh >> 6;
        const int col = (j < DH) ? (h * DH + j) : (CDIM + h * DH + (j - DH));
        wkvT[i] = __float2bfloat16(w_kv[k * (2 * CDIM) + col]);
    } else if (i < NH * 64 * CDIM + NH * DH * QCDIM) { // 18432: wqT[h][j][k] * scale
        const int i2 = i - NH * 64 * CDIM;
        const int k = i2 % QCDIM, jh = i2 / QCDIM;
        const int j = jh & 31, h = jh >> 5;
        wqT[i2] = __float2bfloat16(w_q[k * CDIM + h * DH + j] * SCALE);
    } else {                                           // 18432: wpT[n][k]
        const int i3 = i - NH * 64 * CDIM - NH * DH * QCDIM;
        const int k = i3 % CDIM, n = i3 / CDIM;
        wpT[i3] = __float2bfloat16(w_proj[k * QCDIM + n]);
    }
}

__global__ __launch_bounds__(512, 4)
void attn_fused(const float* __restrict__ kv, const float* __restrict__ q,
                const float* __restrict__ b_kv, const float* __restrict__ b_q,
                const char* __restrict__ wsro, bf16* __restrict__ O)
{
    __shared__ __align__(16) char smem[LDS_TOT];
    bf16* sK   = (bf16*)(smem + LDS_K);
    bf16* sVT  = (bf16*)(smem + LDS_VT);
    bf16* sStg = (bf16*)(smem + LDS_STG);
    bf16* sP   = (bf16*)(smem + LDS_P);
    bf16* sWkv = (bf16*)(smem + LDS_WKV);
    bf16* sWq  = (bf16*)(smem + LDS_WQ);
    bf16* sQ   = (bf16*)(smem + LDS_SQ);

    const int b = blockIdx.x, h = blockIdx.y;
    const int t = threadIdx.x;
    const int wave = t >> 6, lane = t & 63, quad = lane >> 4, l16 = lane & 15;
    const f32x4 ZV = {0.f, 0.f, 0.f, 0.f};

    const float* biasM  = (const float*)(wsro + OFF_BIAS);
    const bf16*  wkvT_g = (const bf16*)(wsro + OFF_WKVT) + h * 64 * CDIM;
    const bf16*  wqT_g  = (const bf16*)(wsro + OFF_WQT) + h * DH * QCDIM;

    // stage wkvT (once): contiguous bf16 copy into padded rows
    for (int f = t; f < 1536; f += 512) {              // 64*192/8
        const int j = f / 24, k8 = f % 24;
        *(uint4*)&sWkv[j * 200 + k8 * 8] = *(const uint4*)&wkvT_g[j * CDIM + k8 * 8];
    }

    // ---------------- Phase A: kvp head slice = kv_b @ wkv_slice ----------------
    f32x4 acc[4];
    #pragma unroll
    for (int i = 0; i < 4; ++i) acc[i] = ZV;

    for (int half = 0; half < 2; ++half) {
        for (int f = t; f < 3072; f += 512) {          // 128 rows x 24 float4
            const int r = f / 24, c4 = f % 24;
            const float4 v = *(const float4*)&kv[((size_t)b * NKV + r) * CDIM + half * QCDIM + c4 * 4];
            __align__(8) bf16 tmp[4] = {__float2bfloat16(v.x), __float2bfloat16(v.y),
                                        __float2bfloat16(v.z), __float2bfloat16(v.w)};
            *(uint2*)&sStg[r * 104 + c4 * 4] = *(uint2*)tmp;
        }
        __syncthreads();
        #pragma unroll
        for (int kk = 0; kk < 3; ++kk) {
            const s16x8 a = *(const s16x8*)&sStg[(wave * 16 + l16) * 104 + kk * 32 + quad * 8];
            #pragma unroll
            for (int tl = 0; tl < 4; ++tl) {
                const s16x8 bb = *(const s16x8*)&sWkv[(tl * 16 + l16) * 200 + half * QCDIM + kk * 32 + quad * 8];
                acc[tl] = MFMA16(a, bb, acc[tl]);
            }
        }
        __syncthreads();
    }
    // epilogue: +bias, K -> sK row-major, V -> sVT transposed
    #pragma unroll
    for (int tl = 0; tl < 4; ++tl) {
        const int j = tl * 16 + l16;
        const float bkv = (j < DH) ? b_kv[h * DH + j] : b_kv[CDIM + h * DH + (j - DH)];
        #pragma unroll
        for (int r = 0; r < 4; ++r) {
            const int m = wave * 16 + quad * 4 + r;
            const float v = acc[tl][r] + bkv;
            if (j < DH) sK[m * 40 + j] = __float2bfloat16(v);
            else        sVT[(j - DH) * 136 + m] = __float2bfloat16(v);
        }
    }
    // stage wqT into region D (wkvT readers all done: synced above)
    for (int f = t; f < 384; f += 512) {               // 32*96/8
        const int j = f / 12, k8 = f % 12;
        *(uint4*)&sWq[j * 104 + k8 * 8] = *(const uint4*)&wqT_g[j * QCDIM + k8 * 8];
    }

    // ---------------- Phase B: q-chunks of 128 rows ----------------
    for (int qc = 0; qc < 4; ++qc) {
        __syncthreads();   // prev chunk's sP/sStg readers done; sK/sVT/wqT visible
        for (int f = t; f < 3072; f += 512) {          // stage q chunk fp32->bf16
            const int r = f / 24, c4 = f % 24;
            const float4 v = *(const float4*)&q[((size_t)b * NQ + qc * 128 + r) * QCDIM + c4 * 4];
            __align__(8) bf16 tmp[4] = {__float2bfloat16(v.x), __float2bfloat16(v.y),
                                        __float2bfloat16(v.z), __float2bfloat16(v.w)};
            *(uint2*)&sStg[r * 104 + c4 * 4] = *(uint2*)tmp;
        }
        __syncthreads();

        // (a) Q' = q_chunk @ wqT (pre-scaled), +b_q*scale -> sQ bf16
        f32x4 qacc[2];
        qacc[0] = ZV; qacc[1] = ZV;
        #pragma unroll
        for (int kk = 0; kk < 3; ++kk) {
            const s16x8 a = *(const s16x8*)&sStg[(wave * 16 + l16) * 104 + kk * 32 + quad * 8];
            #pragma unroll
            for (int tl = 0; tl < 2; ++tl) {
                const s16x8 bb = *(const s16x8*)&sWq[(tl * 16 + l16) * 104 + kk * 32 + quad * 8];
                qacc[tl] = MFMA16(a, bb, qacc[tl]);
            }
        }
        #pragma unroll
        for (int tl = 0; tl < 2; ++tl) {
            const int cc = tl * 16 + l16;
            const float bq = b_q[h * DH + cc] * SCALE;
            #pragma unroll
            for (int r = 0; r < 4; ++r)
                sQ[(wave * 16 + quad * 4 + r) * 40 + cc] = __float2bfloat16(qacc[tl][r] + bq);
        }
        __syncthreads();

        // (b) S = Q' K'^T (K=32 -> 1 MFMA/tile), +bias, softmax -> sP bf16
        f32x4 sacc[8];
        {
            const s16x8 a = *(const s16x8*)&sQ[(wave * 16 + l16) * 40 + quad * 8];
            #pragma unroll
            for (int tl = 0; tl < 8; ++tl) {
                const s16x8 bb = *(const s16x8*)&sK[(tl * 16 + l16) * 40 + quad * 8];
                sacc[tl] = MFMA16(a, bb, ZV);
            }
        }
        #pragma unroll
        for (int r = 0; r < 4; ++r) {
            const int qrow = qc * 128 + wave * 16 + quad * 4 + r;
            const float* brow = biasM + (((size_t)h * NQ + qrow) << 7) + l16;
            float v[8];
            float mx = -1e30f;
            #pragma unroll
            for (int tl = 0; tl < 8; ++tl) {
                v[tl] = sacc[tl][r] + brow[tl * 16];
                mx = fmaxf(mx, v[tl]);
            }
            #pragma unroll
            for (int off = 1; off < 16; off <<= 1) mx = fmaxf(mx, __shfl_xor(mx, off));
            float sum = 0.f;
            #pragma unroll
            for (int tl = 0; tl < 8; ++tl) { v[tl] = __expf(v[tl] - mx); sum += v[tl]; }
            #pragma unroll
            for (int off = 1; off < 16; off <<= 1) sum += __shfl_xor(sum, off);
            const float inv = 1.f / sum;
            const int prow = wave * 16 + quad * 4 + r;
            #pragma unroll
            for (int tl = 0; tl < 8; ++tl)
                sP[prow * 136 + tl * 16 + l16] = __float2bfloat16(v[tl] * inv);
        }
        __syncthreads();

        // (c) O = P V  -> bf16 to ws
        f32x4 oacc[2];
        oacc[0] = ZV; oacc[1] = ZV;
        #pragma unroll
        for (int kk = 0; kk < 4; ++kk) {
            const s16x8 a = *(const s16x8*)&sP[(wave * 16 + l16) * 136 + kk * 32 + quad * 8];
            #pragma unroll
            for (int tl = 0; tl < 2; ++tl) {
                const s16x8 bb = *(const s16x8*)&sVT[(tl * 16 + l16) * 136 + kk * 32 + quad * 8];
                oacc[tl] = MFMA16(a, bb, oacc[tl]);
            }
        }
        #pragma unroll
        for (int tl = 0; tl < 2; ++tl)
            #pragma unroll
            for (int r = 0; r < 4; ++r)
                O[((size_t)(b * NQ + qc * 128 + wave * 16 + quad * 4 + r)) * CDIM
                  + h * DH + tl * 16 + l16] = __float2bfloat16(oacc[tl][r]);
    }
}

// out (131072 x 96 fp32) = O_bf16 (131072 x 192) @ w_proj + b_proj
__global__ __launch_bounds__(256)
void final_proj(const bf16* __restrict__ O, const bf16* __restrict__ wpT,
                const float* __restrict__ b_proj, float* __restrict__ out)
{
    __shared__ __align__(16) bf16 sO[64 * 200];     // 25600 B
    __shared__ __align__(16) bf16 sW[96 * 200];     // 38400 B
    const int row0 = blockIdx.x * 64;
    const int t = threadIdx.x;
    const int wave = t >> 6, lane = t & 63, quad = lane >> 4, l16 = lane & 15;
    const f32x4 ZV = {0.f, 0.f, 0.f, 0.f};

    for (int f = t; f < 1536; f += 256) {           // 64*192/8
        const int r = f / 24, c8 = f % 24;
        *(uint4*)&sO[r * 200 + c8 * 8] = *(const uint4*)&O[((size_t)(row0 + r)) * CDIM + c8 * 8];
    }
    for (int f = t; f < 2304; f += 256) {           // 96*192/8
        const int r = f / 24, c8 = f % 24;
        *(uint4*)&sW[r * 200 + c8 * 8] = *(const uint4*)&wpT[r * CDIM + c8 * 8];
    }
    __syncthreads();

    f32x4 acc[6];
    #pragma unroll
    for (int i = 0; i < 6; ++i) acc[i] = ZV;
    #pragma unroll
    for (int kk = 0; kk < 6; ++kk) {
        const s16x8 a = *(const s16x8*)&sO[(wave * 16 + l16) * 200 + kk * 32 + quad * 8];
        #pragma unroll
        for (int tl = 0; tl < 6; ++tl) {
            const s16x8 bb = *(const s16x8*)&sW[(tl * 16 + l16) * 200 + kk * 32 + quad * 8];
            acc[tl] = MFMA16(a, bb, acc[tl]);
        }
    }
    #pragma unroll
    for (int tl = 0; tl < 6; ++tl) {
        const float bp = b_proj[tl * 16 + l16];
        #pragma unroll
        for (int r = 0; r < 4; ++r)
            out[(size_t)(row0 + wave * 16 + quad * 4 + r) * QCDIM + tl * 16 + l16] = acc[tl][r] + bp;
    }
}

extern "C" void kernel_launch(void* const* d_in, const int* in_sizes, int n_in,
                              void* d_out, int out_size, void* d_ws, size_t ws_size,
                              hipStream_t stream)
{
    const float* kv       = (const float*)d_in[0];
    const float* q        = (const float*)d_in[1];
    const float* w_kv     = (const float*)d_in[2];
    const float* b_kv     = (const float*)d_in[3];
    const float* w_q      = (const float*)d_in[4];
    const float* b_q      = (const float*)d_in[5];
    const float* w_proj   = (const float*)d_in[6];
    const float* b_proj   = (const float*)d_in[7];
    const float* bias_tab = (const float*)d_in[8];
    const int*   rel_idx  = (const int*)d_in[9];
    char* ws = (char*)d_ws;

    precomp_bias<<<1536, 256, 0, stream>>>(bias_tab, rel_idx, (float*)(ws + OFF_BIAS));
    precomp_w<<<432, 256, 0, stream>>>(w_kv, w_q, w_proj,
                                       (bf16*)(ws + OFF_WKVT), (bf16*)(ws + OFF_WQT),
                                       (bf16*)(ws + OFF_WPT));
    attn_fused<<<dim3(B_, NH), 512, 0, stream>>>(kv, q, b_kv, b_q,
                                                 (const char*)ws, (bf16*)(ws + OFF_O));
    final_proj<<<(B_ * NQ) / 64, 256, 0, stream>>>((const bf16*)(ws + OFF_O),
                                                   (const bf16*)(ws + OFF_WPT),
                                                   b_proj, (float*)d_out);
}